// Round 9
// baseline (590.005 us; speedup 1.0000x reference)
//
#include <hip/hip_runtime.h>
#include <hip/hip_bf16.h>
#include <stdint.h>

// Problem constants
#define OUT_DIM 4096
#define IN_DIM  4096
#define GROUPSZ 128
#define NGROUPS 32
#define M_TOTAL 8192   // 4 * 2048
#define EPS_Q   1e-12f

// GEMM tiling: 256x256 tile, BK=64, 8 waves (2M x 4N), 16x16x32 MFMA
#define BM 256
#define BN 256
#define BK 64
#define NT (IN_DIM / BK)   // 64 K-tiles

typedef float f32x4   __attribute__((ext_vector_type(4)));
typedef float float4v __attribute__((ext_vector_type(4)));
typedef short bf16x8  __attribute__((ext_vector_type(8)));
typedef unsigned int u32x4 __attribute__((ext_vector_type(4)));

static __device__ __forceinline__ short f2bf(float f) {
    union { float f; unsigned u; } v; v.f = f;
    unsigned r = v.u + 0x7fffu + ((v.u >> 16) & 1u);
    return (short)(r >> 16);
}

#define GLOAD16(gp, lp) __builtin_amdgcn_global_load_lds( \
    (const __attribute__((address_space(1))) void*)(gp),  \
    (__attribute__((address_space(3))) void*)(lp), 16, 0, 0)

// ---------------------------------------------------------------------------
// Kernel 1: dequantize W (bf16, [N][K] = B^T layout). One wave per (o, g).
// ---------------------------------------------------------------------------
__global__ __launch_bounds__(256) void dequant_kernel(
    const float* __restrict__ norms_p, const float* __restrict__ norms_r,
    const int* __restrict__ idx_p, const int* __restrict__ idx_r,
    short* __restrict__ W)
{
    const int gid  = (int)((blockIdx.x * 256u + threadIdx.x) >> 6);
    const int lane = threadIdx.x & 63;
    const size_t base = (size_t)gid * GROUPSZ;

    const int ip0 = idx_p[base + lane];
    const int ip1 = idx_p[base + lane + 64];
    const int ir0 = idx_r[base + lane];
    const int ir1 = idx_r[base + lane + 64];

    const float qp0 = -1.f + (2.f / 15.f) * (float)ip0;
    const float qp1 = -1.f + (2.f / 15.f) * (float)ip1;
    const float qr0 = -1.f + (2.f / 3.f)  * (float)ir0;
    const float qr1 = -1.f + (2.f / 3.f)  * (float)ir1;

    float ssp = qp0 * qp0 + qp1 * qp1;
    float ssr = qr0 * qr0 + qr1 * qr1;
    #pragma unroll
    for (int m = 32; m >= 1; m >>= 1) {
        ssp += __shfl_xor(ssp, m);
        ssr += __shfl_xor(ssr, m);
    }
    const float sp = norms_p[gid] / sqrtf(ssp + EPS_Q);
    const float sr = norms_r[gid] / sqrtf(ssr + EPS_Q);

    W[base + lane]      = f2bf(qp0 * sp + qr0 * sr);
    W[base + lane + 64] = f2bf(qp1 * sp + qr1 * sr);
}

// ---------------------------------------------------------------------------
// GEMM helpers (compile-time indexed everywhere — rule #20)
// ---------------------------------------------------------------------------
template<int HA, int HB>
__device__ __forceinline__ void mfma_quad(f32x4 (&acc)[2][2][4][2],
                                          const bf16x8 (&af)[4][2],
                                          const bf16x8 (&bf)[2][2]) {
#pragma unroll
    for (int m = 0; m < 4; ++m)
#pragma unroll
        for (int n = 0; n < 2; ++n)
#pragma unroll
            for (int kh = 0; kh < 2; ++kh)
                acc[HA][HB][m][n] = __builtin_amdgcn_mfma_f32_16x16x32_bf16(
                    af[m][kh], bf[n][kh], acc[HA][HB][m][n], 0, 0, 0);
}

static __device__ __forceinline__ void rd8(const short* base, int ck0, int ck1,
                                           bf16x8 (&f)[4][2]) {
#pragma unroll
    for (int m = 0; m < 4; ++m) {
        f[m][0] = *(const bf16x8*)(base + m * 1024 + ck0);
        f[m][1] = *(const bf16x8*)(base + m * 1024 + ck1);
    }
}

static __device__ __forceinline__ void rd4(const short* base, int ck0, int ck1,
                                           bf16x8 (&f)[2][2]) {
#pragma unroll
    for (int n = 0; n < 2; ++n) {
        f[n][0] = *(const bf16x8*)(base + n * 1024 + ck0);
        f[n][1] = *(const bf16x8*)(base + n * 1024 + ck1);
    }
}

// pack 8 fp32 (two f32x4) -> 8 bf16 (one u32x4) via RNE cvt_pk
static __device__ __forceinline__ u32x4 pk8(const f32x4& a, const f32x4& b) {
    union { __hip_bfloat162 h[4]; u32x4 u; } p;
    p.h[0] = __float22bfloat162_rn(float2{a[0], a[1]});
    p.h[1] = __float22bfloat162_rn(float2{a[2], a[3]});
    p.h[2] = __float22bfloat162_rn(float2{b[0], b[1]});
    p.h[3] = __float22bfloat162_rn(float2{b[2], b[3]});
    return p.u;
}

#define BARRIER()  asm volatile("s_barrier" ::: "memory")
#define SCHEDBAR() __builtin_amdgcn_sched_barrier(0)
#define LGKMC(N)   do { asm volatile("s_waitcnt lgkmcnt(" #N ")" ::: "memory"); \
                        SCHEDBAR(); } while (0)
#define WAITV(N)   asm volatile("s_waitcnt vmcnt(" #N ")" ::: "memory")

// ---------------------------------------------------------------------------
// Kernel 2 (fused): C[M][N] = X[M][K](fp32) @ W[N][K]^T + bias, fp32 out.
// A is reg-staged from fp32 x with in-register RNE cvt to bf16 (cast kernel
// eliminated); B staged via global_load_lds as before. Deferred-quad kept.
//
// Per steady tile t, vmem issue order (per thread, 12/tile):
//   A0(t+1) 4 reg-loads, A1(t+1) 4 reg-loads, B0(t+1) 2 DMA, B1(t+1) 2 DMA
// Schedule:
//  batch-1: rd A0(t)(8)+B0(t)(4); ds_write A1(t) (held bf16 regs);
//           issue the 12 above; [PEND quad(1,1) of t-1];
//           lgkm(0) -> quad(0,0); WAITV(12) [drains B1(t)]; BARRIER
//  batch-2: rd B1(t)(4) then A1(t)(8);
//           lgkm(8) -> quad(0,1); lgkm(0) -> quad(1,0);
//           WAITV(8) [drains A0(t+1)] -> cvt+ds_write A0(t+1) into ob;
//           WAITV(2) [drains A1(t+1)+B0(t+1); leaves B1(t+1)];
//           cvt A1(t+1) -> bf16 hold; lgkm(0); BARRIER
// WAR windows checked per region against the 2 barriers/tile (A1(sb) last
// read t-2 b2; A0(ob)/B0(ob) last read t-1 b1; B1(ob) reads drained at
// t-1 lgkm(8) before the end barrier).
// LDS 128 KiB: buf*32768 + {A0:0, A1:8192, B0:16384, B1:24576} shorts.
// Chunk swizzle: LDS chunk = global chunk ^ (row&7) (both sides).
// ---------------------------------------------------------------------------
__global__ __launch_bounds__(512, 2) void gemm_kernel(
    const float* __restrict__ Xf,  // [M][K] fp32 (A source)
    const short* __restrict__ Bg,  // [N][K] bf16
    const float* __restrict__ bias,
    float* __restrict__ C)
{
    __shared__ short lds[65536];   // 128 KiB

    const int tid  = threadIdx.x;
    const int lane = tid & 63;
    const int wid  = tid >> 6;     // 0..7
    const int wr   = wid >> 2;     // 0..1 (M)
    const int wc   = wid & 3;      // 0..3 (N)
    const int fr   = lane & 15;
    const int lq   = lane >> 4;    // 0..3

    // bijective XCD swizzle (nwg = 512, divisible by 8)
    const int nwg = gridDim.x;
    const int cpx = nwg >> 3;
    const int wg  = ((int)blockIdx.x & 7) * cpx + ((int)blockIdx.x >> 3);
    const int ntile = wg & 15;              // N/BN = 16
    const int mtile = wg >> 4;              // M/BM = 32
    const uint32_t brow = (uint32_t)mtile * BM;
    const uint32_t bcol = (uint32_t)ntile * BN;

    // staging: slot s: row r = s>>3, lds chunk c = s&7; thread owns s=tid,
    // s=tid+512. global chunk = c ^ (r&7).
    const uint32_t sr_ = (uint32_t)(tid >> 3);
    const uint32_t gc_ = (uint32_t)((tid & 7) ^ ((tid >> 3) & 7));
    const float* aSrc = Xf + (size_t)(brow + sr_) * IN_DIM + gc_ * 8;
    const uint32_t bOffB = (bcol + sr_) * IN_DIM + gc_ * 8;

    auto stageB = [&](uint32_t extra, short* dstRegion) {
        GLOAD16(Bg + bOffB + extra,            dstRegion + tid * 8);
        GLOAD16(Bg + bOffB + extra + 262144u,  dstRegion + tid * 8 + 4096);
    };
    auto issueA = [&](uint32_t extra, f32x4 (&h)[4]) {
        const float* p = aSrc + extra;
        h[0] = *(const f32x4*)(p);
        h[1] = *(const f32x4*)(p + 4);
        h[2] = *(const f32x4*)(p + 262144u);
        h[3] = *(const f32x4*)(p + 262144u + 4);
    };

    // fragment read offsets (shorts): row*64 + ((kh*4+kc)^(fr&7))*8
    const int c0  = (lq ^ (fr & 7));
    const int ck0 = c0 * 8;
    const int ck1 = (c0 ^ 4) * 8;
    const int aRd = (wr * 64 + fr) * 64;
    const int bRd = (wc * 32 + fr) * 64;

    f32x4  acc[2][2][4][2] = {};
    bf16x8 af[4][2], af2[4][2], bf0[2][2], bf1[2][2];
    f32x4  hA0n[4], hA1n[4];
    u32x4  hA1pk0, hA1pk1;   // A1(t) held as packed bf16

    // ---- prologue: tile 0 + streams primed to steady state ----
    issueA(0u,       hA0n);                 // A0(0) (oldest)
    issueA(524288u,  hA1n);                 // A1(0)
    SCHEDBAR();
    stageB(0u,       lds + 16384);          // B0(0)
    stageB(524288u,  lds + 24576);          // B1(0)
    SCHEDBAR();
    WAITV(8);                               // A0(0) landed
    *(u32x4*)(lds + tid * 8)        = pk8(hA0n[0], hA0n[1]);
    *(u32x4*)(lds + tid * 8 + 4096) = pk8(hA0n[2], hA0n[3]);
    WAITV(2);                               // A1(0), B0(0) landed; B1(0) in flight
    hA1pk0 = pk8(hA1n[0], hA1n[1]);
    hA1pk1 = pk8(hA1n[2], hA1n[3]);
    LGKMC(0);
    BARRIER();

#define TILE_BODY(T, PEND, ISS, WAIT_MID, DO_TAIL, BAR_END) do {              \
    short* sb = lds + (((T) & 1) ? 32768 : 0);                                \
    short* ob = lds + (((T) & 1) ? 0 : 32768);                                \
    /* batch-1: reads + A1(T) write-back + next-tile issues */                \
    rd8(sb + aRd, ck0, ck1, af);                                              \
    rd4(sb + 16384 + bRd, ck0, ck1, bf0);                                     \
    *(u32x4*)(sb + 8192 + tid * 8)        = hA1pk0;                           \
    *(u32x4*)(sb + 8192 + tid * 8 + 4096) = hA1pk1;                           \
    SCHEDBAR();                                                               \
    if (ISS) {                                                                \
        issueA((uint32_t)((T) + 1) * 64u, hA0n);                              \
        issueA(524288u + (uint32_t)((T) + 1) * 64u, hA1n);                    \
        SCHEDBAR();                                                           \
        stageB((uint32_t)((T) + 1) * 64u, ob + 16384);                        \
        stageB(524288u + (uint32_t)((T) + 1) * 64u, ob + 24576);              \
        SCHEDBAR();                                                           \
    }                                                                         \
    if (PEND) {                                                               \
        __builtin_amdgcn_s_setprio(1); mfma_quad<1,1>(acc, af2, bf1);         \
        __builtin_amdgcn_s_setprio(0);                                        \
    }                                                                         \
    LGKMC(0);                                                                 \
    __builtin_amdgcn_s_setprio(1); mfma_quad<0,0>(acc, af, bf0);              \
    __builtin_amdgcn_s_setprio(0);                                            \
    WAIT_MID;                                                                 \
    BARRIER();                                                                \
    /* batch-2 */                                                             \
    rd4(sb + 24576 + bRd, ck0, ck1, bf1);                                     \
    SCHEDBAR();                                                               \
    rd8(sb + 8192 + aRd, ck0, ck1, af2);                                      \
    LGKMC(8);   /* bf1 landed; af2 may still be in flight */                  \
    __builtin_amdgcn_s_setprio(1); mfma_quad<0,1>(acc, af, bf1);              \
    __builtin_amdgcn_s_setprio(0);                                            \
    LGKMC(0);                                                                 \
    __builtin_amdgcn_s_setprio(1); mfma_quad<1,0>(acc, af2, bf0);             \
    __builtin_amdgcn_s_setprio(0);                                            \
    if (ISS) {                                                                \
        WAITV(8);   /* A0(T+1) landed */                                      \
        *(u32x4*)(ob + tid * 8)        = pk8(hA0n[0], hA0n[1]);               \
        *(u32x4*)(ob + tid * 8 + 4096) = pk8(hA0n[2], hA0n[3]);               \
        WAITV(2);   /* A1(T+1)+B0(T+1) landed; B1(T+1) in flight */           \
        hA1pk0 = pk8(hA1n[0], hA1n[1]);                                       \
        hA1pk1 = pk8(hA1n[2], hA1n[3]);                                       \
    }                                                                         \
    if (DO_TAIL) {                                                            \
        __builtin_amdgcn_s_setprio(1); mfma_quad<1,1>(acc, af2, bf1);         \
        __builtin_amdgcn_s_setprio(0);                                        \
    }                                                                         \
    LGKMC(0);                                                                 \
    if (BAR_END) BARRIER();                                                   \
} while (0)

    TILE_BODY(0, 0, 1, WAITV(12), 0, 1);
    #pragma unroll 1
    for (int t = 1; t <= NT - 2; ++t) {
        TILE_BODY(t, 1, 1, WAITV(12), 0, 1);
    }
    TILE_BODY(NT - 1, 1, 0, WAITV(0), 1, 0);
#undef TILE_BODY

    // epilogue: C/D layout col = lane&15, row = lq*4 + reg
    #pragma unroll
    for (int hA = 0; hA < 2; ++hA)
    #pragma unroll
    for (int hB = 0; hB < 2; ++hB)
    #pragma unroll
    for (int n = 0; n < 2; ++n) {
        const int col = (int)bcol + hB * 128 + wc * 32 + n * 16 + fr;
        const float bv = bias[col];
        #pragma unroll
        for (int m = 0; m < 4; ++m) {
            const size_t row0 = (size_t)brow + hA * 128 + wr * 64 + m * 16 + lq * 4;
            #pragma unroll
            for (int r = 0; r < 4; ++r)
                C[(row0 + r) * OUT_DIM + col] = acc[hA][hB][m][n][r] + bv;
        }
    }
}

// ---------------------------------------------------------------------------
extern "C" void kernel_launch(void* const* d_in, const int* in_sizes, int n_in,
                              void* d_out, int out_size, void* d_ws, size_t ws_size,
                              hipStream_t stream)
{
    const float* x        = (const float*)d_in[0];
    const float* norms_p  = (const float*)d_in[1];
    const float* norms_r  = (const float*)d_in[2];
    const float* bias     = (const float*)d_in[3];
    const int*   idx_p    = (const int*)d_in[4];
    const int*   idx_r    = (const int*)d_in[5];
    float*       out      = (float*)d_out;

    // workspace: W only (32 MB bf16 [N][K]); cast kernel eliminated
    short* wq = (short*)d_ws;

    dequant_kernel<<<(OUT_DIM * NGROUPS) / 4, 256, 0, stream>>>(
        norms_p, norms_r, idx_p, idx_r, wq);

    gemm_kernel<<<(M_TOTAL / BM) * (OUT_DIM / BN), 512, 0, stream>>>(x, wq, bias, out);
}